// Round 1
// baseline (435.304 us; speedup 1.0000x reference)
//
#include <hip/hip_runtime.h>
#include <stdint.h>

#define B_N 2048
#define Z_N 128
#define A_N 4
#define D_N 50000
#define EPS_F 1e-8f

typedef __attribute__((ext_vector_type(8))) short short8;
typedef __attribute__((ext_vector_type(4))) float f32x4;

__device__ __forceinline__ unsigned short f2bf(float f) {
  unsigned int u = __builtin_bit_cast(unsigned int, f);
  u += 0x7FFFu + ((u >> 16) & 1u);   // RNE
  return (unsigned short)(u >> 16);
}

// ------------------------------------------------------------------
// P1: normalize batch_x rows, route samples into per-action lists
// ------------------------------------------------------------------
__global__ void k_qnorm_route(const float* __restrict__ x, const int* __restrict__ act,
                              float* __restrict__ qn, int* __restrict__ counts,
                              int* __restrict__ lists) {
  int w = threadIdx.x >> 6, lane = threadIdx.x & 63;
  int row = blockIdx.x * 4 + w;                 // < 2048
  const float2 v = ((const float2*)(x + (size_t)row * Z_N))[lane];
  float ss = v.x * v.x + v.y * v.y;
#pragma unroll
  for (int m = 1; m < 64; m <<= 1) ss += __shfl_xor(ss, m);
  float inv = 1.0f / (sqrtf(ss) + EPS_F);
  float2 o; o.x = v.x * inv; o.y = v.y * inv;
  ((float2*)(qn + (size_t)row * Z_N))[lane] = o;
  if (lane == 0) {
    int a = act[row];
    int pos = atomicAdd(&counts[a], 1);
    lists[a * B_N + pos] = row;
  }
}

// ------------------------------------------------------------------
// P2: normalize keys rows -> bf16 Kn[a][d][z]
// ------------------------------------------------------------------
__global__ void k_keynorm(const float* __restrict__ keys, unsigned short* __restrict__ kn) {
  int w = threadIdx.x >> 6, lane = threadIdx.x & 63;
  size_t row = (size_t)blockIdx.x * 4 + w;      // < A*D = 200000
  const float2 v = ((const float2*)(keys + row * Z_N))[lane];
  float ss = v.x * v.x + v.y * v.y;
#pragma unroll
  for (int m = 1; m < 64; m <<= 1) ss += __shfl_xor(ss, m);
  float inv = 1.0f / (sqrtf(ss) + EPS_F);
  unsigned short2_t; // placeholder avoided
  unsigned int packed = ((unsigned int)f2bf(v.y * inv) << 16) | f2bf(v.x * inv);
  ((unsigned int*)(kn + row * Z_N))[lane] = packed;
}

// ------------------------------------------------------------------
// P3: transpose vals -> bf16 Vt[a][z][d]
// ------------------------------------------------------------------
__global__ void k_vtrans(const float* __restrict__ vals, unsigned short* __restrict__ vt) {
  __shared__ float tile[64][65];
  int a = blockIdx.z, d0 = blockIdx.x * 64, z0 = blockIdx.y * 64;
  int t = threadIdx.x;
  int r = t >> 4, c4 = (t & 15) * 4;
#pragma unroll
  for (int i = 0; i < 4; ++i) {
    int dr = r + i * 16, d = d0 + dr;
    if (d < D_N) {
      const float4 v = *(const float4*)(vals + ((size_t)a * D_N + d) * Z_N + z0 + c4);
      tile[dr][c4 + 0] = v.x; tile[dr][c4 + 1] = v.y;
      tile[dr][c4 + 2] = v.z; tile[dr][c4 + 3] = v.w;
    }
  }
  __syncthreads();
  int zz = t >> 2, dg = (t & 3) * 16;
  if (d0 + dg < D_N) {                           // D % 16 == 0 -> group fully valid
    union { unsigned short u[16]; uint4 q[2]; } pk;
#pragma unroll
    for (int j = 0; j < 16; ++j) pk.u[j] = f2bf(tile[dg + j][zz]);
    unsigned short* dst = vt + ((size_t)a * Z_N + z0 + zz) * D_N + d0 + dg;
    ((uint4*)dst)[0] = pk.q[0];
    ((uint4*)dst)[1] = pk.q[1];
  }
}

// ------------------------------------------------------------------
// F: routed flash attention, bf16 MFMA 16x16x32, chunked over D
// ------------------------------------------------------------------
#define TILE_B 128
#define KT 32
#define CHUNK 1568   // 49*32 ; 32 chunks cover 50176 >= D
#define NITER 49

__launch_bounds__(256, 2)
__global__ void k_flash(const unsigned short* __restrict__ kn,
                        const unsigned short* __restrict__ vt,
                        const float* __restrict__ qn,
                        const int* __restrict__ counts,
                        const int* __restrict__ lists,
                        float* __restrict__ acc,
                        float* __restrict__ sume) {
  int a = blockIdx.z, ty = blockIdx.y;
  int nb = counts[a];
  if (ty * TILE_B >= nb) return;

  __shared__ unsigned short Kl[KT * 136];       // [key][z], pad 136
  __shared__ unsigned short Vl[128 * 40];       // [z][key], pad 40
  __shared__ unsigned short Pl[4][32 * 40];     // per-wave P tile [sample][key], pad 40

  int t = threadIdx.x;
  int w = t >> 6, lane = t & 63;
  int lq = lane >> 4, ln = lane & 15;

  const unsigned short* kn_a = kn + (size_t)a * D_N * Z_N;
  const unsigned short* vt_a = vt + (size_t)a * Z_N * D_N;
  const int* list_a = lists + a * B_N;

  // Q fragments: A-layout, lane holds Q[sample=ln][z = c*32 + lq*8 + j]
  short8 qf[2][4];
#pragma unroll
  for (int mt = 0; mt < 2; ++mt) {
    int g = ty * TILE_B + w * 32 + mt * 16 + ln;
    bool valid = g < nb;
    int si = valid ? list_a[g] : 0;
#pragma unroll
    for (int c = 0; c < 4; ++c) {
      float4 f0 = {0.f, 0.f, 0.f, 0.f}, f1 = {0.f, 0.f, 0.f, 0.f};
      if (valid) {
        const float* qp = qn + (size_t)si * Z_N + c * 32 + lq * 8;
        f0 = *(const float4*)qp;
        f1 = *(const float4*)(qp + 4);
      }
      short8 s;
      s[0] = (short)f2bf(f0.x); s[1] = (short)f2bf(f0.y);
      s[2] = (short)f2bf(f0.z); s[3] = (short)f2bf(f0.w);
      s[4] = (short)f2bf(f1.x); s[5] = (short)f2bf(f1.y);
      s[6] = (short)f2bf(f1.z); s[7] = (short)f2bf(f1.w);
      qf[mt][c] = s;
    }
  }

  f32x4 O[2][8];
#pragma unroll
  for (int mt = 0; mt < 2; ++mt)
#pragma unroll
    for (int zt = 0; zt < 8; ++zt) O[mt][zt] = (f32x4){0.f, 0.f, 0.f, 0.f};
  float rs[2][4] = {{0.f, 0.f, 0.f, 0.f}, {0.f, 0.f, 0.f, 0.f}};

  int d_base = blockIdx.x * CHUNK;
  int sk_key = t >> 3, sk_z = (t & 7) * 16;     // K staging: 32B per thread
  int sv_z = t >> 1, sv_k = (t & 1) * 16;       // V staging: 32B per thread

  for (int kt = 0; kt < NITER; ++kt) {
    int d0 = d_base + kt * KT;
    if (d0 >= D_N) break;                       // uniform
    __syncthreads();
    {   // stage K tile [32][128] bf16 -> padded rows of 136
      int key = d0 + sk_key;
      if (key < D_N) {
        const uint4* src = (const uint4*)(kn_a + (size_t)key * Z_N + sk_z);
        uint4* dst = (uint4*)&Kl[sk_key * 136 + sk_z];
        dst[0] = src[0]; dst[1] = src[1];
      }
    }
    {   // stage V tile [128][32] bf16 (already transposed in ws) -> padded rows of 40
      int kk = d0 + sv_k;
      const unsigned short* src = vt_a + (size_t)sv_z * D_N + kk;
      uint4* dst = (uint4*)&Vl[sv_z * 40 + sv_k];
      if (kk < D_N)     dst[0] = *(const uint4*)src;       // D%8==0 -> full 8 valid
      if (kk + 8 < D_N) dst[1] = *(const uint4*)(src + 8);
    }
    __syncthreads();

    // S = Qn . Kn^T   (M=16 samples, N=16 keys, K=Z accumulated over 4 chunks)
    f32x4 S[2][2];
#pragma unroll
    for (int nt = 0; nt < 2; ++nt) {
      short8 kf[4];
#pragma unroll
      for (int c = 0; c < 4; ++c)
        kf[c] = *(const short8*)&Kl[(nt * 16 + ln) * 136 + c * 32 + lq * 8];
#pragma unroll
      for (int mt = 0; mt < 2; ++mt) {
        f32x4 s4 = (f32x4){0.f, 0.f, 0.f, 0.f};
#pragma unroll
        for (int c = 0; c < 4; ++c)
          s4 = __builtin_amdgcn_mfma_f32_16x16x32_bf16(qf[mt][c], kf[c], s4, 0, 0, 0);
        S[mt][nt] = s4;
      }
    }

    // exp (no max-sub needed: |sim|<=~1), rowsum partials, P -> LDS (C->A layout)
#pragma unroll
    for (int mt = 0; mt < 2; ++mt)
#pragma unroll
      for (int nt = 0; nt < 2; ++nt) {
        bool kv = (d0 + nt * 16 + ln) < D_N;
#pragma unroll
        for (int r = 0; r < 4; ++r) {
          float e = kv ? __expf(S[mt][nt][r]) : 0.f;
          rs[mt][r] += e;
          Pl[w][(mt * 16 + lq * 4 + r) * 40 + nt * 16 + ln] = f2bf(e);
        }
      }

    // O += P . V   (A-frag from per-wave P tile; same-wave DS ops are in-order)
    short8 pf0 = *(const short8*)&Pl[w][(ln) * 40 + lq * 8];
    short8 pf1 = *(const short8*)&Pl[w][(16 + ln) * 40 + lq * 8];
#pragma unroll
    for (int zt = 0; zt < 8; ++zt) {
      short8 vf = *(const short8*)&Vl[(zt * 16 + ln) * 40 + lq * 8];
      O[0][zt] = __builtin_amdgcn_mfma_f32_16x16x32_bf16(pf0, vf, O[0][zt], 0, 0, 0);
      O[1][zt] = __builtin_amdgcn_mfma_f32_16x16x32_bf16(pf1, vf, O[1][zt], 0, 0, 0);
    }
  }

  // full rowsums: reduce over the 16 lanes of each quad-group
#pragma unroll
  for (int mt = 0; mt < 2; ++mt)
#pragma unroll
    for (int r = 0; r < 4; ++r) {
      float v = rs[mt][r];
      v += __shfl_xor(v, 1); v += __shfl_xor(v, 2);
      v += __shfl_xor(v, 4); v += __shfl_xor(v, 8);
      rs[mt][r] = v;
    }

  // scatter partials: C-layout rows = lq*4+r, col z = ln
#pragma unroll
  for (int mt = 0; mt < 2; ++mt)
#pragma unroll
    for (int r = 0; r < 4; ++r) {
      int g = ty * TILE_B + w * 32 + mt * 16 + lq * 4 + r;
      if (g < nb) {
        int si = list_a[g];
        float* arow = acc + (size_t)si * Z_N + ln;
#pragma unroll
        for (int zt = 0; zt < 8; ++zt) atomicAdd(arow + zt * 16, O[mt][zt][r]);
        if (ln == 0) atomicAdd(&sume[si], rs[mt][r]);
      }
    }
}

// ------------------------------------------------------------------
// F2: pred = acc/sume, accumulate sum of squared error
// ------------------------------------------------------------------
__global__ void k_loss(const float* __restrict__ acc, const float* __restrict__ sume,
                       const float* __restrict__ nxt, float* __restrict__ loss) {
  int w = threadIdx.x >> 6, lane = threadIdx.x & 63;
  int row = blockIdx.x * 4 + w;
  float inv = 1.0f / sume[row];
  const float2 p2 = ((const float2*)(acc + (size_t)row * Z_N))[lane];
  const float2 n2 = ((const float2*)(nxt + (size_t)row * Z_N))[lane];
  float dx = p2.x * inv - n2.x, dy = p2.y * inv - n2.y;
  float s = dx * dx + dy * dy;
#pragma unroll
  for (int m = 1; m < 64; m <<= 1) s += __shfl_xor(s, m);
  if (lane == 0) atomicAdd(loss, s);
}

__global__ void k_final(const float* __restrict__ loss, float* __restrict__ out) {
  out[0] = loss[0] * (1.0f / (float)(B_N * Z_N));
}

// ------------------------------------------------------------------
// ws layout (bytes):
//  qn      @ 0          1,048,576
//  acc     @ 1,048,576  1,048,576   (zeroed)
//  sume    @ 2,097,152      8,192   (zeroed)
//  counts  @ 2,105,344         16   (zeroed)
//  loss    @ 2,105,360         16   (zeroed)
//  lists   @ 2,105,376     32,768
//  Kn bf16 @ 2,138,368 51,200,000
//  Vt bf16 @ 53,338,368 51,200,000   -> total ~104.5 MB
// ------------------------------------------------------------------
extern "C" void kernel_launch(void* const* d_in, const int* in_sizes, int n_in,
                              void* d_out, int out_size, void* d_ws, size_t ws_size,
                              hipStream_t stream) {
  const float* x    = (const float*)d_in[0];
  const float* nxt  = (const float*)d_in[1];
  const float* keys = (const float*)d_in[2];
  const float* vals = (const float*)d_in[3];
  const int*   act  = (const int*)d_in[4];

  char* ws = (char*)d_ws;
  float* qn     = (float*)(ws + 0);
  float* acc    = (float*)(ws + 1048576);
  float* sume   = (float*)(ws + 2097152);
  int*   counts = (int*)(ws + 2105344);
  float* loss   = (float*)(ws + 2105360);
  int*   lists  = (int*)(ws + 2105376);
  unsigned short* kn = (unsigned short*)(ws + 2138368);
  unsigned short* vt = (unsigned short*)(ws + 53338368);

  hipMemsetAsync(ws + 1048576, 0, 1056800, stream);

  k_qnorm_route<<<512, 256, 0, stream>>>(x, act, qn, counts, lists);
  k_keynorm<<<50000, 256, 0, stream>>>(keys, kn);
  k_vtrans<<<dim3(782, 2, A_N), 256, 0, stream>>>(vals, vt);
  k_flash<<<dim3(32, 16, A_N), 256, 0, stream>>>(kn, vt, qn, counts, lists, acc, sume);
  k_loss<<<512, 256, 0, stream>>>(acc, sume, nxt, loss);
  k_final<<<1, 1, 0, stream>>>(loss, (float*)d_out);
}